// Round 5
// baseline (119.574 us; speedup 1.0000x reference)
//
#include <hip/hip_runtime.h>
#include <hip/hip_bf16.h>
#include <stdint.h>

#define BATCH 4096
#define N_TOT 8192
#define D_DIM 256
#define SHIFT 150.0f
#define SQRT2 1.41421356237309515f

typedef __bf16 bf16_t;
typedef bf16_t bf16x8 __attribute__((ext_vector_type(8)));
typedef bf16_t bf16x4 __attribute__((ext_vector_type(4)));
typedef float f32x4 __attribute__((ext_vector_type(4)));

// global -> LDS direct copy, 16B per lane. LDS dest is wave-uniform base;
// HW scatters lane*16B linearly (cannot swizzle the dest -> swizzle the src).
__device__ __forceinline__ void gl_lds16(const void* g, void* l) {
  __builtin_amdgcn_global_load_lds(
      (const __attribute__((address_space(1))) void*)(uintptr_t)g,
      (__attribute__((address_space(3))) void*)(uint32_t)(uintptr_t)l,
      16, 0, 0);
}

// Fused: bf16 convert (x sqrt2), positive-pair dot partials, Zrow zero-init.
// 1024 blocks x 256 threads; wave w of block b owns row r = b*4+w.
__global__ void k_prep(const float* __restrict__ hi, const float* __restrict__ hj,
                       bf16_t* __restrict__ hb, float* __restrict__ Zrow,
                       float* __restrict__ posPartial) {
  const int wave = threadIdx.x >> 6, lane = threadIdx.x & 63;
  const int r = blockIdx.x * 4 + wave;
  const size_t off = (size_t)r * D_DIM + lane * 4;
  float4 a = *(const float4*)(hi + off);
  float4 b = *(const float4*)(hj + off);

  bf16x4 oa, ob;
  oa[0] = (bf16_t)(a.x * SQRT2); oa[1] = (bf16_t)(a.y * SQRT2);
  oa[2] = (bf16_t)(a.z * SQRT2); oa[3] = (bf16_t)(a.w * SQRT2);
  ob[0] = (bf16_t)(b.x * SQRT2); ob[1] = (bf16_t)(b.y * SQRT2);
  ob[2] = (bf16_t)(b.z * SQRT2); ob[3] = (bf16_t)(b.w * SQRT2);
  *(bf16x4*)(hb + off) = oa;
  *(bf16x4*)(hb + (size_t)BATCH * D_DIM + off) = ob;

  float d = a.x * b.x + a.y * b.y + a.z * b.z + a.w * b.w;
#pragma unroll
  for (int o = 32; o >= 1; o >>= 1) d += __shfl_xor(d, o);
  __shared__ float ps[4];
  if (lane == 0) ps[wave] = d;
  // zero 8 Zrow entries per block (8192 total over 1024 blocks)
  if (threadIdx.x < 8) Zrow[blockIdx.x * 8 + threadIdx.x] = 0.f;
  __syncthreads();
  if (threadIdx.x == 0) posPartial[blockIdx.x] = ps[0] + ps[1] + ps[2] + ps[3];
}

// Upper-triangular 128x128 tiles of sim = hb.hb^T; fused exp(sim-SHIFT) with
// row-sum AND (off-diag) col-sum accumulation into Zrow. 2080 blocks, 4 waves.
// A panel preloaded into 128 VGPRs and PINNED with an asm liveness barrier
// (round-4 failure: without the pin, hipcc sinks the loads back into the loop
// -> serial L2 latency per k-step; VGPR_Count 100 proved it). B panel (64KB)
// staged once into XOR-swizzled LDS. One barrier; then a barrier-free stream
// of 32 ds_read_b128 + 128 MFMA per wave with static indices only.
__global__ __launch_bounds__(256, 2) void k_gemm(const bf16_t* __restrict__ hb,
                                                 float* __restrict__ Zrow) {
  // decode linear block id -> (bi <= bj) triangular pair
  const int t = blockIdx.x;
  int bj = (int)((sqrtf(8.0f * (float)t + 1.0f) - 1.0f) * 0.5f);
  while ((bj + 1) * (bj + 2) / 2 <= t) ++bj;
  while (bj * (bj + 1) / 2 > t) --bj;
  const int bi = t - bj * (bj + 1) / 2;
  const int rBase = bi * 128;
  const int cBase = bj * 128;
  const bool diag = (bi == bj);

  // B panel: LDS 16B-chunk c of row r holds GLOBAL chunk c ^ (r&15) ->
  // frag reads (16 rows x same k-chunk) spread 2 lanes/bank = free (m136).
  __shared__ __align__(16) bf16_t Bs[128][D_DIM];

  const int tid = threadIdx.x;
  const int lane = tid & 63;
  const int wave = tid >> 6;  // 0..3
  const int wm = wave >> 1, wn = wave & 1;
  const int quad = lane >> 4, l16 = lane & 15;

  // ---- stage B panel (32 rows/wave, 16 x gl_lds16, issued FIRST) --------
  {
    const int s = lane >> 5;    // row-within-pair
    const int c = lane & 31;    // 16B chunk within row
#pragma unroll
    for (int i = 0; i < 16; ++i) {
      const int rloc = wave * 32 + i * 2 + s;
      const int gc = c ^ (rloc & 15);  // pre-swizzled global chunk
      gl_lds16(hb + (size_t)(cBase + rloc) * D_DIM + gc * 8,
               &Bs[wave * 32 + i * 2][0]);
    }
  }

  // ---- preload FULL A wave-panel into registers (latency paid once) -----
  // af[mt][ks]: lane (quad,l16) holds A[rBase+wm*64+mt*16+l16][ks*32+quad*8..+7]
  bf16x8 af[4][8];
#pragma unroll
  for (int mt = 0; mt < 4; ++mt) {
    const bf16_t* ab =
        hb + (size_t)(rBase + wm * 64 + mt * 16 + l16) * D_DIM + quad * 8;
#pragma unroll
    for (int ks = 0; ks < 8; ++ks) af[mt][ks] = *(const bf16x8*)(ab + ks * 32);
  }
  // PIN: asm reads+writes each fragment -> loads cannot be sunk past here.
#pragma unroll
  for (int mt = 0; mt < 4; ++mt)
#pragma unroll
    for (int ks = 0; ks < 8; ++ks)
      asm volatile("" : "+v"(af[mt][ks]));

  f32x4 acc[4][4];
#pragma unroll
  for (int i = 0; i < 4; ++i)
#pragma unroll
    for (int j = 0; j < 4; ++j) acc[i][j] = (f32x4){0.f, 0.f, 0.f, 0.f};

  __syncthreads();  // single barrier: B panel ready, af resident

  // ---- barrier-free MFMA stream: 8 k-steps x {4 ds_read_b128 + 16 MFMA} --
#pragma unroll
  for (int ks = 0; ks < 8; ++ks) {
    bf16x8 bfr[4];
#pragma unroll
    for (int nt = 0; nt < 4; ++nt) {
      const int cc = ((ks * 4 + quad) ^ l16) * 8;  // un-swizzle (row&15==l16)
      bfr[nt] = *(const bf16x8*)&Bs[wn * 64 + nt * 16 + l16][cc];
    }
#pragma unroll
    for (int mt = 0; mt < 4; ++mt)
#pragma unroll
      for (int nt = 0; nt < 4; ++nt)
        acc[mt][nt] = __builtin_amdgcn_mfma_f32_16x16x32_bf16(af[mt][ks], bfr[nt],
                                                              acc[mt][nt], 0, 0, 0);
  }

  // epilogue: e = exp(sim - SHIFT); row sums always, col sums for off-diag
  // (symmetry: entry (r,c) also stands in for (c,r)).
  const int rW = rBase + wm * 64 + quad * 4;
  const int cW = cBase + wn * 64 + l16;
  float colAcc[4] = {0.f, 0.f, 0.f, 0.f};
#pragma unroll
  for (int mt = 0; mt < 4; ++mt) {
#pragma unroll
    for (int rg = 0; rg < 4; ++rg) {
      const int rr = rW + mt * 16 + rg;
      float s = 0.f;
#pragma unroll
      for (int nt = 0; nt < 4; ++nt) {
        float e = __expf(acc[mt][nt][rg] - SHIFT);
        if (diag && (rr == cW + nt * 16)) e = 0.f;  // mask self-similarity
        s += e;
        colAcc[nt] += e;
      }
      s += __shfl_xor(s, 1);
      s += __shfl_xor(s, 2);
      s += __shfl_xor(s, 4);
      s += __shfl_xor(s, 8);
      if (l16 == 0) atomicAdd(&Zrow[rr], s);
    }
  }
  if (!diag) {
#pragma unroll
    for (int nt = 0; nt < 4; ++nt) {
      float c = colAcc[nt];
      c += __shfl_xor(c, 16);
      c += __shfl_xor(c, 32);
      if (lane < 16) atomicAdd(&Zrow[cW + nt * 16], c);
    }
  }
}

// One block: loss = mean(log Z + SHIFT) - sum(dot)/2048
__global__ void k_finish(const float* __restrict__ Zrow,
                         const float* __restrict__ posPartial,
                         float* __restrict__ out) {
  const int t = threadIdx.x;  // 0..1023
  float4 z0 = *(const float4*)(Zrow + t * 8);
  float4 z1 = *(const float4*)(Zrow + t * 8 + 4);
  float sl = __logf(z0.x) + __logf(z0.y) + __logf(z0.z) + __logf(z0.w) +
             __logf(z1.x) + __logf(z1.y) + __logf(z1.z) + __logf(z1.w);
  float sp = posPartial[t];
#pragma unroll
  for (int o = 32; o >= 1; o >>= 1) {
    sl += __shfl_xor(sl, o);
    sp += __shfl_xor(sp, o);
  }
  __shared__ float pl[16], pp[16];
  const int wave = t >> 6, lane = t & 63;
  if (lane == 0) { pl[wave] = sl; pp[wave] = sp; }
  __syncthreads();
  if (t == 0) {
    float L = 0.f, P = 0.f;
    for (int i = 0; i < 16; ++i) { L += pl[i]; P += pp[i]; }
    out[0] = L / (float)N_TOT + SHIFT - P / 2048.0f;
  }
}

extern "C" void kernel_launch(void* const* d_in, const int* in_sizes, int n_in,
                              void* d_out, int out_size, void* d_ws, size_t ws_size,
                              hipStream_t stream) {
  const float* hi = (const float*)d_in[0];
  const float* hj = (const float*)d_in[1];
  float* out = (float*)d_out;

  bf16_t* hb = (bf16_t*)d_ws;                                        // 4 MB
  float* Zrow = (float*)((char*)d_ws + (size_t)N_TOT * D_DIM * 2);   // 32 KB
  float* posPartial = Zrow + N_TOT;                                  // 4 KB

  k_prep<<<1024, 256, 0, stream>>>(hi, hj, hb, Zrow, posPartial);
  k_gemm<<<2080, 256, 0, stream>>>(hb, Zrow);
  k_finish<<<1, 1024, 0, stream>>>(Zrow, posPartial, out);
}

// Round 6
// 103.161 us; speedup vs baseline: 1.1591x; 1.1591x over previous
//
#include <hip/hip_runtime.h>
#include <hip/hip_bf16.h>
#include <stdint.h>

#define BATCH 4096
#define N_TOT 8192
#define D_DIM 256
#define SHIFT 150.0f
#define SQRT2 1.41421356237309515f

typedef __bf16 bf16_t;
typedef bf16_t bf16x8 __attribute__((ext_vector_type(8)));
typedef bf16_t bf16x4 __attribute__((ext_vector_type(4)));
typedef float f32x4 __attribute__((ext_vector_type(4)));

// global -> LDS direct copy, 16B per lane. LDS dest is wave-uniform base;
// HW scatters lane*16B linearly (cannot swizzle the dest -> swizzle the src).
__device__ __forceinline__ void gl_lds16(const void* g, void* l) {
  __builtin_amdgcn_global_load_lds(
      (const __attribute__((address_space(1))) void*)(uintptr_t)g,
      (__attribute__((address_space(3))) void*)(uint32_t)(uintptr_t)l,
      16, 0, 0);
}

// Fused: bf16 convert (x sqrt2), positive-pair dot partials, Zrow zero-init.
// 1024 blocks x 256 threads; wave w of block b owns row r = b*4+w.
__global__ void k_prep(const float* __restrict__ hi, const float* __restrict__ hj,
                       bf16_t* __restrict__ hb, float* __restrict__ Zrow,
                       float* __restrict__ posPartial) {
  const int wave = threadIdx.x >> 6, lane = threadIdx.x & 63;
  const int r = blockIdx.x * 4 + wave;
  const size_t off = (size_t)r * D_DIM + lane * 4;
  float4 a = *(const float4*)(hi + off);
  float4 b = *(const float4*)(hj + off);

  bf16x4 oa, ob;
  oa[0] = (bf16_t)(a.x * SQRT2); oa[1] = (bf16_t)(a.y * SQRT2);
  oa[2] = (bf16_t)(a.z * SQRT2); oa[3] = (bf16_t)(a.w * SQRT2);
  ob[0] = (bf16_t)(b.x * SQRT2); ob[1] = (bf16_t)(b.y * SQRT2);
  ob[2] = (bf16_t)(b.z * SQRT2); ob[3] = (bf16_t)(b.w * SQRT2);
  *(bf16x4*)(hb + off) = oa;
  *(bf16x4*)(hb + (size_t)BATCH * D_DIM + off) = ob;

  float d = a.x * b.x + a.y * b.y + a.z * b.z + a.w * b.w;
#pragma unroll
  for (int o = 32; o >= 1; o >>= 1) d += __shfl_xor(d, o);
  __shared__ float ps[4];
  if (lane == 0) ps[wave] = d;
  // zero 8 Zrow entries per block (8192 total over 1024 blocks)
  if (threadIdx.x < 8) Zrow[blockIdx.x * 8 + threadIdx.x] = 0.f;
  __syncthreads();
  if (threadIdx.x == 0) posPartial[blockIdx.x] = ps[0] + ps[1] + ps[2] + ps[3];
}

// Upper-triangular 128x128 tiles of sim = hb.hb^T; fused exp(sim-SHIFT) with
// row-sum AND (off-diag) col-sum accumulation into Zrow. 2080 blocks, 4 waves.
// Geometry is round-0's verified one (BK=64, XOR-swizzle staging, acc[4][4]).
// NEW: counted-vmcnt double-buffer pipeline (T3+T4 minimum). Per slab k:
//   STAGE(k+1 -> buf^1)            (8 gl_lds16/wave, stays in flight)
//   s_waitcnt vmcnt(8)             (slab k's 8 landed; k+1's NOT drained)
//   s_barrier                      (all waves -> slab k fully in LDS)
//   ds_read frags; lgkmcnt(0); sched_barrier(0)   (reads in regs; rule #18)
//   32 MFMA
//   s_barrier                      (WAR: buf k free before next overwrite)
// vmcnt retires in issue order (m135), so vmcnt(8) is exactly "slab k done".
// __syncthreads is NOT used in the loop -- it would drain vmcnt(0).
__global__ __launch_bounds__(256, 2) void k_gemm(const bf16_t* __restrict__ hb,
                                                 float* __restrict__ Zrow) {
  // decode linear block id -> (bi <= bj) triangular pair
  const int t = blockIdx.x;
  int bj = (int)((sqrtf(8.0f * (float)t + 1.0f) - 1.0f) * 0.5f);
  while ((bj + 1) * (bj + 2) / 2 <= t) ++bj;
  while (bj * (bj + 1) / 2 > t) --bj;
  const int bi = t - bj * (bj + 1) / 2;
  const int rBase = bi * 128;
  const int cBase = bj * 128;
  const bool diag = (bi == bj);

  __shared__ __align__(16) bf16_t As[2][128][64];
  __shared__ __align__(16) bf16_t Bs[2][128][64];
  const int tid = threadIdx.x;
  const int lane = tid & 63;
  const int wave = tid >> 6;  // 0..3

  // staging: waves 0,1 -> As halves; waves 2,3 -> Bs halves (r0-verified).
  // XOR-swizzle the 16B chunk on the GLOBAL side so LDS[row][c] holds global
  // chunk c ^ (row&7)  (row&7 == lane>>3 here) -> conflict-free frag reads.
  const int half = wave & 1;
  const size_t stageRow = (size_t)((wave < 2 ? rBase : cBase) + half * 64);
  const int c_src = (lane & 7) ^ (lane >> 3);
  const bf16_t* gsrc = hb + stageRow * D_DIM + (size_t)(lane >> 3) * D_DIM + c_src * 8;
  bf16_t* lbase = (wave < 2) ? &As[0][half * 64][0] : &Bs[0][half * 64][0];

  // stage slab s (64 K-cols) into buffer b: 8 x gl_lds16 (8 rows each).
  auto STAGE = [&](int s, int b) {
#pragma unroll
    for (int i = 0; i < 8; ++i)
      gl_lds16(gsrc + (size_t)i * 8 * D_DIM + s * 64,
               lbase + b * (128 * 64) + i * 8 * 64);
  };

  const int wm = wave >> 1, wn = wave & 1;
  const int quad = lane >> 4, l16 = lane & 15;
  const int sw = l16 & 7;  // read-side un-swizzle key

  f32x4 acc[4][4];
#pragma unroll
  for (int i = 0; i < 4; ++i)
#pragma unroll
    for (int j = 0; j < 4; ++j) acc[i][j] = (f32x4){0.f, 0.f, 0.f, 0.f};

  STAGE(0, 0);  // prologue: slab 0 in flight

#pragma unroll
  for (int k = 0; k < 4; ++k) {
    const int b = k & 1;
    if (k + 1 < 4) {
      STAGE(k + 1, b ^ 1);  // next slab's loads fly across the barrier
      asm volatile("s_waitcnt vmcnt(8)" ::: "memory");  // slab k landed
    } else {
      asm volatile("s_waitcnt vmcnt(0)" ::: "memory");  // last slab: drain
    }
    __builtin_amdgcn_s_barrier();  // bar1: slab k fully visible in LDS

    bf16x8 af[2][4], bfr[2][4];
#pragma unroll
    for (int ks = 0; ks < 2; ++ks) {
      const int chunk = ((ks * 4 + quad) ^ sw) * 8;
#pragma unroll
      for (int mt = 0; mt < 4; ++mt)
        af[ks][mt] = *(const bf16x8*)&As[b][wm * 64 + mt * 16 + l16][chunk];
#pragma unroll
      for (int nt = 0; nt < 4; ++nt)
        bfr[ks][nt] = *(const bf16x8*)&Bs[b][wn * 64 + nt * 16 + l16][chunk];
    }
    asm volatile("s_waitcnt lgkmcnt(0)" ::: "memory");  // reads in registers
    __builtin_amdgcn_sched_barrier(0);                  // rule #18 fence

#pragma unroll
    for (int ks = 0; ks < 2; ++ks)
#pragma unroll
      for (int mt = 0; mt < 4; ++mt)
#pragma unroll
        for (int nt = 0; nt < 4; ++nt)
          acc[mt][nt] = __builtin_amdgcn_mfma_f32_16x16x32_bf16(
              af[ks][mt], bfr[ks][nt], acc[mt][nt], 0, 0, 0);

    __builtin_amdgcn_s_barrier();  // bar2: buffer b free for overwrite
  }

  // epilogue: e = exp(sim - SHIFT); row sums always, col sums for off-diag
  // (symmetry: entry (r,c) also stands in for (c,r)).
  const int rW = rBase + wm * 64 + quad * 4;
  const int cW = cBase + wn * 64 + l16;
  float colAcc[4] = {0.f, 0.f, 0.f, 0.f};
#pragma unroll
  for (int mt = 0; mt < 4; ++mt) {
#pragma unroll
    for (int rg = 0; rg < 4; ++rg) {
      const int rr = rW + mt * 16 + rg;
      float s = 0.f;
#pragma unroll
      for (int nt = 0; nt < 4; ++nt) {
        float e = __expf(acc[mt][nt][rg] - SHIFT);
        if (diag && (rr == cW + nt * 16)) e = 0.f;  // mask self-similarity
        s += e;
        colAcc[nt] += e;
      }
      s += __shfl_xor(s, 1);
      s += __shfl_xor(s, 2);
      s += __shfl_xor(s, 4);
      s += __shfl_xor(s, 8);
      if (l16 == 0) atomicAdd(&Zrow[rr], s);
    }
  }
  if (!diag) {
#pragma unroll
    for (int nt = 0; nt < 4; ++nt) {
      float c = colAcc[nt];
      c += __shfl_xor(c, 16);
      c += __shfl_xor(c, 32);
      if (lane < 16) atomicAdd(&Zrow[cW + nt * 16], c);
    }
  }
}

// One block: loss = mean(log Z + SHIFT) - sum(dot)/2048
__global__ void k_finish(const float* __restrict__ Zrow,
                         const float* __restrict__ posPartial,
                         float* __restrict__ out) {
  const int t = threadIdx.x;  // 0..1023
  float4 z0 = *(const float4*)(Zrow + t * 8);
  float4 z1 = *(const float4*)(Zrow + t * 8 + 4);
  float sl = __logf(z0.x) + __logf(z0.y) + __logf(z0.z) + __logf(z0.w) +
             __logf(z1.x) + __logf(z1.y) + __logf(z1.z) + __logf(z1.w);
  float sp = posPartial[t];
#pragma unroll
  for (int o = 32; o >= 1; o >>= 1) {
    sl += __shfl_xor(sl, o);
    sp += __shfl_xor(sp, o);
  }
  __shared__ float pl[16], pp[16];
  const int wave = t >> 6, lane = t & 63;
  if (lane == 0) { pl[wave] = sl; pp[wave] = sp; }
  __syncthreads();
  if (t == 0) {
    float L = 0.f, P = 0.f;
    for (int i = 0; i < 16; ++i) { L += pl[i]; P += pp[i]; }
    out[0] = L / (float)N_TOT + SHIFT - P / 2048.0f;
  }
}

extern "C" void kernel_launch(void* const* d_in, const int* in_sizes, int n_in,
                              void* d_out, int out_size, void* d_ws, size_t ws_size,
                              hipStream_t stream) {
  const float* hi = (const float*)d_in[0];
  const float* hj = (const float*)d_in[1];
  float* out = (float*)d_out;

  bf16_t* hb = (bf16_t*)d_ws;                                        // 4 MB
  float* Zrow = (float*)((char*)d_ws + (size_t)N_TOT * D_DIM * 2);   // 32 KB
  float* posPartial = Zrow + N_TOT;                                  // 4 KB

  k_prep<<<1024, 256, 0, stream>>>(hi, hj, hb, Zrow, posPartial);
  k_gemm<<<2080, 256, 0, stream>>>(hb, Zrow);
  k_finish<<<1, 1024, 0, stream>>>(Zrow, posPartial, out);
}

// Round 7
// 101.007 us; speedup vs baseline: 1.1838x; 1.0213x over previous
//
#include <hip/hip_runtime.h>
#include <hip/hip_bf16.h>
#include <stdint.h>

#define BATCH 4096
#define N_TOT 8192
#define D_DIM 256
#define SHIFT 150.0f
#define SQRT2 1.41421356237309515f
#define NTILE 32            // 8192 / 256
#define NBLK 528            // 32*33/2 triangular 256x256 tiles

typedef __bf16 bf16_t;
typedef bf16_t bf16x8 __attribute__((ext_vector_type(8)));
typedef bf16_t bf16x4 __attribute__((ext_vector_type(4)));
typedef float f32x4 __attribute__((ext_vector_type(4)));

// global -> LDS direct copy, 16B per lane. LDS dest is wave-uniform base;
// HW scatters lane*16B linearly (cannot swizzle the dest -> swizzle the src).
__device__ __forceinline__ void gl_lds16(const void* g, void* l) {
  __builtin_amdgcn_global_load_lds(
      (const __attribute__((address_space(1))) void*)(uintptr_t)g,
      (__attribute__((address_space(3))) void*)(uint32_t)(uintptr_t)l,
      16, 0, 0);
}

// Fused: bf16 convert (x sqrt2), positive-pair dot partials, Zrow zero-init.
// 1024 blocks x 256 threads; wave w of block b owns row r = b*4+w.
__global__ void k_prep(const float* __restrict__ hi, const float* __restrict__ hj,
                       bf16_t* __restrict__ hb, float* __restrict__ Zrow,
                       float* __restrict__ posPartial) {
  const int wave = threadIdx.x >> 6, lane = threadIdx.x & 63;
  const int r = blockIdx.x * 4 + wave;
  const size_t off = (size_t)r * D_DIM + lane * 4;
  float4 a = *(const float4*)(hi + off);
  float4 b = *(const float4*)(hj + off);

  bf16x4 oa, ob;
  oa[0] = (bf16_t)(a.x * SQRT2); oa[1] = (bf16_t)(a.y * SQRT2);
  oa[2] = (bf16_t)(a.z * SQRT2); oa[3] = (bf16_t)(a.w * SQRT2);
  ob[0] = (bf16_t)(b.x * SQRT2); ob[1] = (bf16_t)(b.y * SQRT2);
  ob[2] = (bf16_t)(b.z * SQRT2); ob[3] = (bf16_t)(b.w * SQRT2);
  *(bf16x4*)(hb + off) = oa;
  *(bf16x4*)(hb + (size_t)BATCH * D_DIM + off) = ob;

  float d = a.x * b.x + a.y * b.y + a.z * b.z + a.w * b.w;
#pragma unroll
  for (int o = 32; o >= 1; o >>= 1) d += __shfl_xor(d, o);
  __shared__ float ps[4];
  if (lane == 0) ps[wave] = d;
  // zero 8 Zrow entries per block (8192 total over 1024 blocks)
  if (threadIdx.x < 8) Zrow[blockIdx.x * 8 + threadIdx.x] = 0.f;
  __syncthreads();
  if (threadIdx.x == 0) posPartial[blockIdx.x] = ps[0] + ps[1] + ps[2] + ps[3];
}

// Upper-triangular 256x256 tiles of sim = hb.hb^T; fused exp(sim-SHIFT) with
// row-sum AND (off-diag) col-sum accumulation into Zrow. 528 blocks, 8 waves.
// WHY 256^2: the 128^2 tile is staging-bound (64 FLOP/B < per-CU L2 balance
// ~72) -- no schedule can fix that (rounds 0-6 all 40-60us). 256^2 doubles
// intensity to 128 FLOP/B -> compute-dominant. Counted-vmcnt dbuf skeleton
// verified in round 6. 1 block/CU (VGPR ~220, 2 waves/SIMD) -- intended.
// Per slab (BK=32, 8 slabs): STAGE(next,4x gl_lds16) -> vmcnt(4) -> s_barrier
// -> 12x ds_read_b128 -> lgkmcnt(0)+sched_barrier -> 32 MFMA -> s_barrier.
__global__ __launch_bounds__(512, 2) void k_gemm(const bf16_t* __restrict__ hb,
                                                 float* __restrict__ Zrow) {
  // decode linear block id -> (bi <= bj) triangular pair
  const int t = blockIdx.x;
  int bj = (int)((sqrtf(8.0f * (float)t + 1.0f) - 1.0f) * 0.5f);
  while ((bj + 1) * (bj + 2) / 2 <= t) ++bj;
  while (bj * (bj + 1) / 2 > t) --bj;
  const int bi = t - bj * (bj + 1) / 2;
  const int rBase = bi * 256;
  const int cBase = bj * 256;
  const bool diag = (bi == bj);

  // [2 buffers][256 rows][32 K] bf16 = 16 KB per buffer per matrix; 64 KB.
  // Swizzle: row has 4 x 16B chunks; LDS[r][c] holds GLOBAL chunk c ^ (r&3)
  // -> each 16B bank-group is read by exactly 8 lanes (balanced, no conflict).
  __shared__ __align__(16) bf16_t As[2][256][32];
  __shared__ __align__(16) bf16_t Bs[2][256][32];
  const int tid = threadIdx.x;
  const int lane = tid & 63;
  const int wave = tid >> 6;  // 0..7

  // ---- staging geometry: waves 0-3 -> As 64-row quarters; 4-7 -> Bs -----
  // LDS dest linear: lane -> row = lane>>2, chunk = lane&3 (16 rows/issue).
  // Source chunk pre-swizzled: (lane&3) ^ (row&3) = (lane&3) ^ ((lane>>2)&3).
  const int sq = wave & 3;
  const size_t stageRow = (size_t)((wave < 4 ? rBase : cBase) + sq * 64);
  const int schunk = (lane & 3) ^ ((lane >> 2) & 3);
  const bf16_t* gsrc =
      hb + (stageRow + (lane >> 2)) * D_DIM + schunk * 8;
  bf16_t* lbase = (wave < 4) ? &As[0][sq * 64][0] : &Bs[0][sq * 64][0];

  // stage slab s (32 K-cols, 64 rows/wave) into buffer b: 4 x gl_lds16.
  auto STAGE = [&](int s, int b) {
#pragma unroll
    for (int i = 0; i < 4; ++i)
      gl_lds16(gsrc + (size_t)(i * 16) * D_DIM + s * 32,
               lbase + b * (256 * 32) + i * 16 * 32);
  };

  // ---- fragment geometry: wave grid 4(row strips of 64) x 2(col 128) ----
  const int wm = wave >> 1, wn = wave & 1;
  const int quad = lane >> 4, l16 = lane & 15;
  const int cc = (quad ^ (l16 & 3)) * 8;  // read-side un-swizzle (row&3==l16&3)

  f32x4 acc[4][8];
#pragma unroll
  for (int i = 0; i < 4; ++i)
#pragma unroll
    for (int j = 0; j < 8; ++j) acc[i][j] = (f32x4){0.f, 0.f, 0.f, 0.f};

  STAGE(0, 0);  // prologue: slab 0 in flight

#pragma unroll
  for (int k = 0; k < 8; ++k) {
    const int b = k & 1;
    if (k + 1 < 8) {
      STAGE(k + 1, b ^ 1);  // next slab's loads fly across the barrier
      asm volatile("s_waitcnt vmcnt(4)" ::: "memory");  // slab k landed
    } else {
      asm volatile("s_waitcnt vmcnt(0)" ::: "memory");  // last slab: drain
    }
    __builtin_amdgcn_s_barrier();  // bar1: slab k fully visible in LDS

    bf16x8 af[4], bfr[8];
#pragma unroll
    for (int mt = 0; mt < 4; ++mt)
      af[mt] = *(const bf16x8*)&As[b][wm * 64 + mt * 16 + l16][cc];
#pragma unroll
    for (int nt = 0; nt < 8; ++nt)
      bfr[nt] = *(const bf16x8*)&Bs[b][wn * 128 + nt * 16 + l16][cc];
    asm volatile("s_waitcnt lgkmcnt(0)" ::: "memory");  // reads in registers
    __builtin_amdgcn_sched_barrier(0);                  // rule #18 fence

#pragma unroll
    for (int mt = 0; mt < 4; ++mt)
#pragma unroll
      for (int nt = 0; nt < 8; ++nt)
        acc[mt][nt] = __builtin_amdgcn_mfma_f32_16x16x32_bf16(
            af[mt], bfr[nt], acc[mt][nt], 0, 0, 0);

    __builtin_amdgcn_s_barrier();  // bar2: buffer b free for overwrite
  }

  // epilogue: e = exp(sim - SHIFT); row sums always, col sums for off-diag
  // (symmetry: entry (r,c) also stands in for (c,r)).
  const int rW = rBase + wm * 64 + quad * 4;
  const int cW = cBase + wn * 128 + l16;
  float colAcc[8] = {0.f, 0.f, 0.f, 0.f, 0.f, 0.f, 0.f, 0.f};
#pragma unroll
  for (int mt = 0; mt < 4; ++mt) {
#pragma unroll
    for (int rg = 0; rg < 4; ++rg) {
      const int rr = rW + mt * 16 + rg;
      float s = 0.f;
#pragma unroll
      for (int nt = 0; nt < 8; ++nt) {
        float e = __expf(acc[mt][nt][rg] - SHIFT);
        if (diag && (rr == cW + nt * 16)) e = 0.f;  // mask self-similarity
        s += e;
        colAcc[nt] += e;
      }
      s += __shfl_xor(s, 1);
      s += __shfl_xor(s, 2);
      s += __shfl_xor(s, 4);
      s += __shfl_xor(s, 8);
      if (l16 == 0) atomicAdd(&Zrow[rr], s);
    }
  }
  if (!diag) {
#pragma unroll
    for (int nt = 0; nt < 8; ++nt) {
      float c = colAcc[nt];
      c += __shfl_xor(c, 16);
      c += __shfl_xor(c, 32);
      if (lane < 16) atomicAdd(&Zrow[cW + nt * 16], c);
    }
  }
}

// One block: loss = mean(log Z + SHIFT) - sum(dot)/2048
__global__ void k_finish(const float* __restrict__ Zrow,
                         const float* __restrict__ posPartial,
                         float* __restrict__ out) {
  const int t = threadIdx.x;  // 0..1023
  float4 z0 = *(const float4*)(Zrow + t * 8);
  float4 z1 = *(const float4*)(Zrow + t * 8 + 4);
  float sl = __logf(z0.x) + __logf(z0.y) + __logf(z0.z) + __logf(z0.w) +
             __logf(z1.x) + __logf(z1.y) + __logf(z1.z) + __logf(z1.w);
  float sp = posPartial[t];
#pragma unroll
  for (int o = 32; o >= 1; o >>= 1) {
    sl += __shfl_xor(sl, o);
    sp += __shfl_xor(sp, o);
  }
  __shared__ float pl[16], pp[16];
  const int wave = t >> 6, lane = t & 63;
  if (lane == 0) { pl[wave] = sl; pp[wave] = sp; }
  __syncthreads();
  if (t == 0) {
    float L = 0.f, P = 0.f;
    for (int i = 0; i < 16; ++i) { L += pl[i]; P += pp[i]; }
    out[0] = L / (float)N_TOT + SHIFT - P / 2048.0f;
  }
}

extern "C" void kernel_launch(void* const* d_in, const int* in_sizes, int n_in,
                              void* d_out, int out_size, void* d_ws, size_t ws_size,
                              hipStream_t stream) {
  const float* hi = (const float*)d_in[0];
  const float* hj = (const float*)d_in[1];
  float* out = (float*)d_out;

  bf16_t* hb = (bf16_t*)d_ws;                                        // 4 MB
  float* Zrow = (float*)((char*)d_ws + (size_t)N_TOT * D_DIM * 2);   // 32 KB
  float* posPartial = Zrow + N_TOT;                                  // 4 KB

  k_prep<<<1024, 256, 0, stream>>>(hi, hj, hb, Zrow, posPartial);
  k_gemm<<<NBLK, 512, 0, stream>>>(hb, Zrow);
  k_finish<<<1, 1024, 0, stream>>>(Zrow, posPartial, out);
}

// Round 9
// 95.332 us; speedup vs baseline: 1.2543x; 1.0595x over previous
//
#include <hip/hip_runtime.h>
#include <hip/hip_bf16.h>
#include <stdint.h>

#define BATCH 4096
#define N_TOT 8192
#define D_DIM 256
#define SHIFT 150.0f
#define SQRT2 1.41421356237309515f

typedef __bf16 bf16_t;
typedef bf16_t bf16x8 __attribute__((ext_vector_type(8)));
typedef bf16_t bf16x4 __attribute__((ext_vector_type(4)));
typedef float f32x4 __attribute__((ext_vector_type(4)));

// global -> LDS direct copy, 16B per lane. LDS dest is wave-uniform base;
// HW scatters lane*16B linearly (cannot swizzle the dest -> swizzle the src).
__device__ __forceinline__ void gl_lds16(const void* g, void* l) {
  __builtin_amdgcn_global_load_lds(
      (const __attribute__((address_space(1))) void*)(uintptr_t)g,
      (__attribute__((address_space(3))) void*)(uint32_t)(uintptr_t)l,
      16, 0, 0);
}

// Fused: bf16 convert (x sqrt2), positive-pair dot partials, Zrow zero-init.
// 1024 blocks x 256 threads; wave w of block b owns row r = b*4+w.
__global__ void k_prep(const float* __restrict__ hi, const float* __restrict__ hj,
                       bf16_t* __restrict__ hb, float* __restrict__ Zrow,
                       float* __restrict__ posPartial) {
  const int wave = threadIdx.x >> 6, lane = threadIdx.x & 63;
  const int r = blockIdx.x * 4 + wave;
  const size_t off = (size_t)r * D_DIM + lane * 4;
  float4 a = *(const float4*)(hi + off);
  float4 b = *(const float4*)(hj + off);

  bf16x4 oa, ob;
  oa[0] = (bf16_t)(a.x * SQRT2); oa[1] = (bf16_t)(a.y * SQRT2);
  oa[2] = (bf16_t)(a.z * SQRT2); oa[3] = (bf16_t)(a.w * SQRT2);
  ob[0] = (bf16_t)(b.x * SQRT2); ob[1] = (bf16_t)(b.y * SQRT2);
  ob[2] = (bf16_t)(b.z * SQRT2); ob[3] = (bf16_t)(b.w * SQRT2);
  *(bf16x4*)(hb + off) = oa;
  *(bf16x4*)(hb + (size_t)BATCH * D_DIM + off) = ob;

  float d = a.x * b.x + a.y * b.y + a.z * b.z + a.w * b.w;
#pragma unroll
  for (int o = 32; o >= 1; o >>= 1) d += __shfl_xor(d, o);
  __shared__ float ps[4];
  if (lane == 0) ps[wave] = d;
  // zero 8 Zrow entries per block (8192 total over 1024 blocks)
  if (threadIdx.x < 8) Zrow[blockIdx.x * 8 + threadIdx.x] = 0.f;
  __syncthreads();
  if (threadIdx.x == 0) posPartial[blockIdx.x] = ps[0] + ps[1] + ps[2] + ps[3];
}

// Upper-triangular 128x128 tiles of sim = hb.hb^T; fused exp(sim-SHIFT) with
// row-sum AND (off-diag) col-sum accumulation into Zrow. 2080 blocks, 4 waves.
// THE UNTESTED MATRIX CELL: counted-vmcnt double-buffer (r6-verified skeleton)
// AND 4 blocks/CU TLP (r0's winning residency). BK=32 -> LDS only 32KB.
// Per slab: STAGE(next, 4x gl_lds16) -> vmcnt(4) [slab k landed, k+1 still in
// flight] -> s_barrier -> 8x ds_read_b128 -> lgkmcnt(0)+sched_barrier(0)
// [rule #18] -> 16 MFMA -> s_barrier [WAR]. No vmcnt(0) inside the loop.
// Swizzle (64B rows, bank pattern repeats every 2 rows): LDS[r][c16] holds
// GLOBAL chunk c16 ^ ((r>>1)&3) -> frag reads are uniform 2-way = free (m136).
// Round-7's (r&3) key was WRONG (rows 0,4,8,12 collided -> 1.6M conflicts).
__global__ __launch_bounds__(256, 4) void k_gemm(const bf16_t* __restrict__ hb,
                                                 float* __restrict__ Zrow) {
  // decode linear block id -> (bi <= bj) triangular pair
  const int t = blockIdx.x;
  int bj = (int)((sqrtf(8.0f * (float)t + 1.0f) - 1.0f) * 0.5f);
  while ((bj + 1) * (bj + 2) / 2 <= t) ++bj;
  while (bj * (bj + 1) / 2 > t) --bj;
  const int bi = t - bj * (bj + 1) / 2;
  const int rBase = bi * 128;
  const int cBase = bj * 128;
  const bool diag = (bi == bj);

  __shared__ __align__(16) bf16_t As[2][128][32];
  __shared__ __align__(16) bf16_t Bs[2][128][32];
  const int tid = threadIdx.x;
  const int lane = tid & 63;
  const int wave = tid >> 6;  // 0..3

  // staging: waves 0,1 -> As halves (64 rows each); waves 2,3 -> Bs halves.
  // One gl_lds16 issue covers 16 rows (lane -> row=lane>>2, chunk=lane&3).
  // Source chunk pre-swizzled: (lane&3) ^ ((row>>1)&3) = (lane&3)^((lane>>3)&3)
  // (row bits 1..2 == lane bits 3..4; issue/half offsets are multiples of 8).
  const int half = wave & 1;
  const size_t stageRow = (size_t)((wave < 2 ? rBase : cBase) + half * 64);
  const int schunk = (lane & 3) ^ ((lane >> 3) & 3);
  const bf16_t* gsrc = hb + (stageRow + (lane >> 2)) * D_DIM + schunk * 8;
  bf16_t* lbase = (wave < 2) ? &As[0][half * 64][0] : &Bs[0][half * 64][0];

  // stage slab s (32 K-cols, 64 rows/wave) into buffer b: 4 x gl_lds16.
  auto STAGE = [&](int s, int b) {
#pragma unroll
    for (int i = 0; i < 4; ++i)
      gl_lds16(gsrc + (size_t)(i * 16) * D_DIM + s * 32,
               lbase + b * (128 * 32) + i * 16 * 32);
  };

  const int wm = wave >> 1, wn = wave & 1;
  const int quad = lane >> 4, l16 = lane & 15;
  // read-side un-swizzle: row = ..+l16 -> key (l16>>1)&3 (bases mult. of 16)
  const int cc = (quad ^ ((l16 >> 1) & 3)) * 8;

  f32x4 acc[4][4];
#pragma unroll
  for (int i = 0; i < 4; ++i)
#pragma unroll
    for (int j = 0; j < 4; ++j) acc[i][j] = (f32x4){0.f, 0.f, 0.f, 0.f};

  STAGE(0, 0);  // prologue: slab 0 in flight

#pragma unroll
  for (int k = 0; k < 8; ++k) {
    const int b = k & 1;
    if (k + 1 < 8) {
      STAGE(k + 1, b ^ 1);  // next slab's loads fly across the barrier
      asm volatile("s_waitcnt vmcnt(4)" ::: "memory");  // slab k landed
    } else {
      asm volatile("s_waitcnt vmcnt(0)" ::: "memory");  // last slab: drain
    }
    __builtin_amdgcn_s_barrier();  // bar1: slab k fully visible in LDS

    bf16x8 af[4], bfr[4];
#pragma unroll
    for (int mt = 0; mt < 4; ++mt)
      af[mt] = *(const bf16x8*)&As[b][wm * 64 + mt * 16 + l16][cc];
#pragma unroll
    for (int nt = 0; nt < 4; ++nt)
      bfr[nt] = *(const bf16x8*)&Bs[b][wn * 64 + nt * 16 + l16][cc];
    asm volatile("s_waitcnt lgkmcnt(0)" ::: "memory");  // reads in registers
    __builtin_amdgcn_sched_barrier(0);                  // rule #18 fence

#pragma unroll
    for (int mt = 0; mt < 4; ++mt)
#pragma unroll
      for (int nt = 0; nt < 4; ++nt)
        acc[mt][nt] = __builtin_amdgcn_mfma_f32_16x16x32_bf16(
            af[mt], bfr[nt], acc[mt][nt], 0, 0, 0);

    __builtin_amdgcn_s_barrier();  // bar2: buffer b free for overwrite
  }

  // epilogue: e = exp(sim - SHIFT); row sums always, col sums for off-diag
  // (symmetry: entry (r,c) also stands in for (c,r)).
  const int rW = rBase + wm * 64 + quad * 4;
  const int cW = cBase + wn * 64 + l16;
  float colAcc[4] = {0.f, 0.f, 0.f, 0.f};
#pragma unroll
  for (int mt = 0; mt < 4; ++mt) {
#pragma unroll
    for (int rg = 0; rg < 4; ++rg) {
      const int rr = rW + mt * 16 + rg;
      float s = 0.f;
#pragma unroll
      for (int nt = 0; nt < 4; ++nt) {
        float e = __expf(acc[mt][nt][rg] - SHIFT);
        if (diag && (rr == cW + nt * 16)) e = 0.f;  // mask self-similarity
        s += e;
        colAcc[nt] += e;
      }
      s += __shfl_xor(s, 1);
      s += __shfl_xor(s, 2);
      s += __shfl_xor(s, 4);
      s += __shfl_xor(s, 8);
      if (l16 == 0) atomicAdd(&Zrow[rr], s);
    }
  }
  if (!diag) {
#pragma unroll
    for (int nt = 0; nt < 4; ++nt) {
      float c = colAcc[nt];
      c += __shfl_xor(c, 16);
      c += __shfl_xor(c, 32);
      if (lane < 16) atomicAdd(&Zrow[cW + nt * 16], c);
    }
  }
}

// One block: loss = mean(log Z + SHIFT) - sum(dot)/2048
__global__ void k_finish(const float* __restrict__ Zrow,
                         const float* __restrict__ posPartial,
                         float* __restrict__ out) {
  const int t = threadIdx.x;  // 0..1023
  float4 z0 = *(const float4*)(Zrow + t * 8);
  float4 z1 = *(const float4*)(Zrow + t * 8 + 4);
  float sl = __logf(z0.x) + __logf(z0.y) + __logf(z0.z) + __logf(z0.w) +
             __logf(z1.x) + __logf(z1.y) + __logf(z1.z) + __logf(z1.w);
  float sp = posPartial[t];
#pragma unroll
  for (int o = 32; o >= 1; o >>= 1) {
    sl += __shfl_xor(sl, o);
    sp += __shfl_xor(sp, o);
  }
  __shared__ float pl[16], pp[16];
  const int wave = t >> 6, lane = t & 63;
  if (lane == 0) { pl[wave] = sl; pp[wave] = sp; }
  __syncthreads();
  if (t == 0) {
    float L = 0.f, P = 0.f;
    for (int i = 0; i < 16; ++i) { L += pl[i]; P += pp[i]; }
    out[0] = L / (float)N_TOT + SHIFT - P / 2048.0f;
  }
}

extern "C" void kernel_launch(void* const* d_in, const int* in_sizes, int n_in,
                              void* d_out, int out_size, void* d_ws, size_t ws_size,
                              hipStream_t stream) {
  const float* hi = (const float*)d_in[0];
  const float* hj = (const float*)d_in[1];
  float* out = (float*)d_out;

  bf16_t* hb = (bf16_t*)d_ws;                                        // 4 MB
  float* Zrow = (float*)((char*)d_ws + (size_t)N_TOT * D_DIM * 2);   // 32 KB
  float* posPartial = Zrow + N_TOT;                                  // 4 KB

  k_prep<<<1024, 256, 0, stream>>>(hi, hj, hb, Zrow, posPartial);
  k_gemm<<<2080, 256, 0, stream>>>(hb, Zrow);
  k_finish<<<1, 1024, 0, stream>>>(Zrow, posPartial, out);
}